// Round 6
// baseline (298.441 us; speedup 1.0000x reference)
//
#include <hip/hip_runtime.h>
#include <hip/hip_fp16.h>
#include <math.h>

#define BLK 256

// ---------------------------------------------------------------------------
// GCNPolicyNetwork: 3-layer improved-GCN + masked softmax + mean-pool value.
// Round 6: agg kernels still latency-bound (occ 41%, 1.1 TB/s vs ~5x traffic
// floor). Now 8 lanes per node: lane = (node<<3)|(g<<2)|sub; the two g-groups
// walk interleaved halves of the node's edge list (stride 2, unroll x4),
// combine partial sums via shfl_xor(4). 2x thread count, half per-thread trip
// count -> 2x memory-level parallelism. hws payloads stay fp16 (L2-resident).
// ---------------------------------------------------------------------------

#define BSH 9                    // 512 nodes per bucket
#define EB 8192                  // edges per binning block
#define BINTH 512                // k_bin block size

// ---- fp16 payload helpers (4 features per lane = 8 B) ----
__device__ inline float4 load_h4(const __half* base, int node, int sub) {
    const uint2* p = reinterpret_cast<const uint2*>(base + ((size_t)node << 4)) + sub;
    uint2 u = *p;
    union { unsigned u; __half2 h; } a, b;
    a.u = u.x; b.u = u.y;
    float2 fa = __half22float2(a.h), fb = __half22float2(b.h);
    return make_float4(fa.x, fa.y, fb.x, fb.y);
}

__device__ inline void store_h4(__half* base, int node, int sub, float4 v) {
    union { unsigned u; __half2 h; } a, b;
    a.h = __floats2half2_rn(v.x, v.y);
    b.h = __floats2half2_rn(v.z, v.w);
    uint2 u; u.x = a.u; u.y = b.u;
    *(reinterpret_cast<uint2*>(base + ((size_t)node << 4)) + sub) = u;
}

// per-block LDS histogram of bucket ids, flush with <=196 global atomics
__global__ void __launch_bounds__(BLK) k_bcount(const int* __restrict__ col,
                                                int* __restrict__ bcnt, int E) {
    __shared__ int hist[256];
    int tid = threadIdx.x;
    int base = blockIdx.x * EB;
    int cnt = min(EB, E - base);
    hist[tid] = 0;
    __syncthreads();
    for (int j = tid; j < cnt; j += BLK)
        atomicAdd(&hist[col[base + j] >> BSH], 1);
    __syncthreads();
    if (hist[tid] > 0) atomicAdd(&bcnt[tid], hist[tid]);
}

// single-block exclusive scan of bucket counts -> gcur (mutable) + bbase (kept)
__global__ void k_bscan(const int* __restrict__ bcnt, int* __restrict__ gcur,
                        int* __restrict__ bbase, int nbuck) {
    __shared__ int s[256];
    int tid = threadIdx.x;
    int v = (tid < nbuck) ? bcnt[tid] : 0;
    s[tid] = v;
    __syncthreads();
    for (int d = 1; d < 256; d <<= 1) {
        int t = (tid >= d) ? s[tid - d] : 0;
        __syncthreads();
        if (tid >= d) s[tid] += t;
        __syncthreads();
    }
    int ex = s[tid] - v;
    gcur[tid] = ex;
    bbase[tid] = ex;
}

// pass 1: LDS multisplit of edges into buckets, coalesced flush to packed[]
__global__ void __launch_bounds__(BINTH) k_bin(const int* __restrict__ row,
                                               const int* __restrict__ col,
                                               int* __restrict__ gcur,
                                               int* __restrict__ packed, int E) {
    __shared__ int stage[EB];            // packed edges, bucket-sorted locally
    __shared__ unsigned char sbuk[EB];   // bucket id per staged slot
    __shared__ int hist[256];
    __shared__ int lscan[256];
    __shared__ int cur[256];
    __shared__ int gbase[256];
    int tid = threadIdx.x;
    int base = blockIdx.x * EB;
    int cnt = min(EB, E - base);

    if (tid < 256) hist[tid] = 0;
    __syncthreads();
    for (int j = tid; j < cnt; j += BINTH) {
        int c = col[base + j];
        atomicAdd(&hist[c >> BSH], 1);
    }
    __syncthreads();
    if (tid < 256) lscan[tid] = hist[tid];
    __syncthreads();
    for (int d = 1; d < 256; d <<= 1) {
        int t = 0;
        if (tid < 256 && tid >= d) t = lscan[tid - d];
        __syncthreads();
        if (tid < 256 && tid >= d) lscan[tid] += t;
        __syncthreads();
    }
    if (tid < 256) {
        int ex = lscan[tid] - hist[tid];
        lscan[tid] = ex;
        cur[tid] = ex;
    }
    __syncthreads();
    for (int j = tid; j < cnt; j += BINTH) {
        int c = col[base + j];
        int r = row[base + j];
        int b = c >> BSH;
        int p = atomicAdd(&cur[b], 1);
        stage[p] = (r << BSH) | (c & ((1 << BSH) - 1));
        sbuk[p] = (unsigned char)b;
    }
    __syncthreads();
    if (tid < 256 && hist[tid] > 0) gbase[tid] = atomicAdd(&gcur[tid], hist[tid]);
    __syncthreads();
    for (int j = tid; j < cnt; j += BINTH) {
        int b = sbuk[j];
        int pos = gbase[b] + (j - lscan[b]);
        packed[pos] = stage[j];
    }
}

// pass 2: per-bucket degree count + scan (-> degi/offs/dinv) + fine placement
__global__ void __launch_bounds__(BLK) k_place(const int* __restrict__ packed,
                                               const int* __restrict__ bbase,
                                               const int* __restrict__ bcnt,
                                               int* __restrict__ degi,
                                               int* __restrict__ offs,
                                               float* __restrict__ dinv,
                                               int* __restrict__ srcs, int n) {
    __shared__ int cnt[1 << BSH];
    __shared__ int lcur[1 << BSH];
    __shared__ int ssum[BLK];
    int tid = threadIdx.x;
    int b = blockIdx.x;
    int nb0 = b << BSH;
    for (int t = tid; t < (1 << BSH); t += BLK) cnt[t] = 0;
    __syncthreads();
    int pbeg = bbase[b];
    int pend = pbeg + bcnt[b];
    for (int j = pbeg + tid; j < pend; j += BLK)
        atomicAdd(&cnt[packed[j] & ((1 << BSH) - 1)], 1);
    __syncthreads();
    int c0 = cnt[2 * tid], c1 = cnt[2 * tid + 1];
    int pair = c0 + c1;
    ssum[tid] = pair;
    __syncthreads();
    for (int d = 1; d < BLK; d <<= 1) {
        int t = (tid >= d) ? ssum[tid - d] : 0;
        __syncthreads();
        if (tid >= d) ssum[tid] += t;
        __syncthreads();
    }
    int ex = ssum[tid] - pair;
    lcur[2 * tid] = ex;
    lcur[2 * tid + 1] = ex + c0;
    int node0 = nb0 + 2 * tid;
    if (node0 < n) {
        degi[node0] = c0;
        offs[node0] = pbeg + ex;
        dinv[node0] = rsqrtf((float)c0 + 2.0f);
    }
    if (node0 + 1 < n) {
        degi[node0 + 1] = c1;
        offs[node0 + 1] = pbeg + ex + c0;
        dinv[node0 + 1] = rsqrtf((float)c1 + 2.0f);
    }
    __syncthreads();
    for (int j = pbeg + tid; j < pend; j += BLK) {
        int v = packed[j];
        int li = v & ((1 << BSH) - 1);
        int r = v >> BSH;
        int slot = atomicAdd(&lcur[li], 1);
        srcs[pbeg + slot] = r;
    }
}

// layer-1 transform: hwsA = dinv * (x @ W1)   (x is N x 3), fp16 store
__global__ void __launch_bounds__(BLK) k_l1(const float* __restrict__ x,
                                            const float* __restrict__ W1,
                                            const float* __restrict__ dinv,
                                            __half* __restrict__ hwsA, int n) {
    __shared__ float w[48];
    if (threadIdx.x < 48) w[threadIdx.x] = W1[threadIdx.x];
    __syncthreads();
    int i = blockIdx.x * BLK + threadIdx.x;
    if (i >= n) return;
    float x0 = x[i * 3 + 0], x1 = x[i * 3 + 1], x2 = x[i * 3 + 2];
    float di = dinv[i];
#pragma unroll
    for (int sub = 0; sub < 4; sub++) {
        float4 o;
        float* op = &o.x;
#pragma unroll
        for (int k = 0; k < 4; k++) {
            int f = sub * 4 + k;
            op[k] = di * (x0 * w[f] + x1 * w[16 + f] + x2 * w[32 + f]);
        }
        store_h4(hwsA, i, sub, o);
    }
}

// 8 lanes per node: sub = feature slice (4 feats), g = edge-list half.
// Group g walks j = beg+g, beg+g+2, ... (stride 2), unroll x4.
// After the loop both groups' partials are combined via shfl_xor(4).
#define GATHER8H(HWS)                                                           \
    float4 acc = make_float4(0.f, 0.f, 0.f, 0.f);                               \
    {                                                                           \
        if (g == 0) {                                                           \
            float4 s0 = load_h4(HWS, i, sub);                                   \
            acc = make_float4(2.f * s0.x, 2.f * s0.y, 2.f * s0.z, 2.f * s0.w);  \
        }                                                                       \
        float4 a1 = make_float4(0.f, 0.f, 0.f, 0.f);                            \
        float4 a2 = a1, a3 = a1;                                                \
        int beg = offs[i], end = beg + degi[i];                                 \
        int j = beg + g;                                                        \
        for (; j + 6 < end; j += 8) {                                           \
            int r0 = srcs[j], r1 = srcs[j + 2], r2 = srcs[j + 4], r3 = srcs[j + 6]; \
            float4 q0 = load_h4(HWS, r0, sub);                                  \
            float4 q1 = load_h4(HWS, r1, sub);                                  \
            float4 q2 = load_h4(HWS, r2, sub);                                  \
            float4 q3 = load_h4(HWS, r3, sub);                                  \
            acc.x += q0.x; acc.y += q0.y; acc.z += q0.z; acc.w += q0.w;         \
            a1.x += q1.x; a1.y += q1.y; a1.z += q1.z; a1.w += q1.w;             \
            a2.x += q2.x; a2.y += q2.y; a2.z += q2.z; a2.w += q2.w;             \
            a3.x += q3.x; a3.y += q3.y; a3.z += q3.z; a3.w += q3.w;             \
        }                                                                       \
        for (; j < end; j += 2) {                                               \
            int r0 = srcs[j];                                                   \
            float4 q0 = load_h4(HWS, r0, sub);                                  \
            acc.x += q0.x; acc.y += q0.y; acc.z += q0.z; acc.w += q0.w;         \
        }                                                                       \
        acc.x += a1.x + a2.x + a3.x;                                            \
        acc.y += a1.y + a2.y + a3.y;                                            \
        acc.z += a1.z + a2.z + a3.z;                                            \
        acc.w += a1.w + a2.w + a3.w;                                            \
        acc.x += __shfl_xor(acc.x, 4);                                          \
        acc.y += __shfl_xor(acc.y, 4);                                          \
        acc.z += __shfl_xor(acc.z, 4);                                          \
        acc.w += __shfl_xor(acc.w, 4);                                          \
    }

// layer-1 aggregate + relu + layer-2 transform: hwsB = dinv * (h1 @ W2)
// 32 nodes/block; each of the node's 8 lanes outputs 2 features (half2 store).
__global__ void __launch_bounds__(BLK) k_agg1(const __half* __restrict__ hwsA,
                                              const int* __restrict__ offs,
                                              const int* __restrict__ degi,
                                              const int* __restrict__ srcs,
                                              const float* __restrict__ dinv,
                                              const float* __restrict__ b1,
                                              const float* __restrict__ W2,
                                              __half* __restrict__ hwsB, int n) {
    __shared__ float w[256];
    __shared__ float bb[16];
    __shared__ float hbuf[32][17];           // +1 pad: conflict-free
    int tid = threadIdx.x;
    w[tid] = W2[tid];
    if (tid < 16) bb[tid] = b1[tid];
    __syncthreads();
    int nl = tid >> 3, g = (tid >> 2) & 1, sub = tid & 3;
    int i = blockIdx.x * 32 + nl;
    bool act = (i < n);
    if (act) {
        float di = dinv[i];
        GATHER8H(hwsA);
        if (g == 0) {
            hbuf[nl][sub * 4 + 0] = fmaxf(di * acc.x + bb[sub * 4 + 0], 0.f);
            hbuf[nl][sub * 4 + 1] = fmaxf(di * acc.y + bb[sub * 4 + 1], 0.f);
            hbuf[nl][sub * 4 + 2] = fmaxf(di * acc.z + bb[sub * 4 + 2], 0.f);
            hbuf[nl][sub * 4 + 3] = fmaxf(di * acc.w + bb[sub * 4 + 3], 0.f);
        }
    }
    __syncthreads();
    if (act) {
        float di = dinv[i];
        const float* hn = hbuf[nl];
        int of = (tid & 7) * 2;              // this lane's 2 output features
        float s0 = 0.f, s1 = 0.f;
#pragma unroll
        for (int f = 0; f < 16; f++) {
            float hv = hn[f];
            s0 += hv * w[f * 16 + of];
            s1 += hv * w[f * 16 + of + 1];
        }
        union { unsigned u; __half2 h; } o;
        o.h = __floats2half2_rn(di * s0, di * s1);
        reinterpret_cast<unsigned*>(hwsB + ((size_t)i << 4))[tid & 7] = o.u;
    }
}

// layer-2 aggregate + relu (-> h2), pool accumulation, layer-3 transform
__global__ void __launch_bounds__(BLK) k_agg2(const __half* __restrict__ hwsB,
                                              const int* __restrict__ offs,
                                              const int* __restrict__ degi,
                                              const int* __restrict__ srcs,
                                              const float* __restrict__ dinv,
                                              const float* __restrict__ b2,
                                              const float* __restrict__ W3,
                                              float* __restrict__ hws3,
                                              float* __restrict__ pool, int n) {
    __shared__ float w3[16];
    __shared__ float bb[16];
    __shared__ float lp[16];
    int tid = threadIdx.x;
    if (tid < 16) { w3[tid] = W3[tid]; bb[tid] = b2[tid]; lp[tid] = 0.f; }
    __syncthreads();
    int nl = tid >> 3, g = (tid >> 2) & 1, sub = tid & 3;
    int i = blockIdx.x * 32 + nl;
    bool act = (i < n);
    float4 h = make_float4(0.f, 0.f, 0.f, 0.f);
    if (act) {
        float di = dinv[i];
        GATHER8H(hwsB);
        if (g == 0) {
            h.x = fmaxf(di * acc.x + bb[sub * 4 + 0], 0.f);
            h.y = fmaxf(di * acc.y + bb[sub * 4 + 1], 0.f);
            h.z = fmaxf(di * acc.z + bb[sub * 4 + 2], 0.f);
            h.w = fmaxf(di * acc.w + bb[sub * 4 + 3], 0.f);
            float p = h.x * w3[sub * 4 + 0] + h.y * w3[sub * 4 + 1]
                    + h.z * w3[sub * 4 + 2] + h.w * w3[sub * 4 + 3];
            p += __shfl_xor(p, 1);
            p += __shfl_xor(p, 2);
            if (sub == 0) hws3[i] = di * p;
        }
    }
    // pool: h==0 on g1 lanes and inactive nodes; reduce over the wave's 8 nodes
    float4 hp = h;
#pragma unroll
    for (int m = 8; m < 64; m <<= 1) {
        hp.x += __shfl_xor(hp.x, m);
        hp.y += __shfl_xor(hp.y, m);
        hp.z += __shfl_xor(hp.z, m);
        hp.w += __shfl_xor(hp.w, m);
    }
    if ((tid & 63) < 4) {                    // node0/g0 lanes hold wave sums
        atomicAdd(&lp[sub * 4 + 0], hp.x);
        atomicAdd(&lp[sub * 4 + 1], hp.y);
        atomicAdd(&lp[sub * 4 + 2], hp.z);
        atomicAdd(&lp[sub * 4 + 3], hp.w);
    }
    __syncthreads();
    if (tid < 16) atomicAdd(&pool[tid], lp[tid]);
}

// layer-3 aggregate -> logits c[n]; per-block max of masked logits
__global__ void __launch_bounds__(BLK) k_agg3(const float* __restrict__ hws3,
                                              const int* __restrict__ offs,
                                              const int* __restrict__ degi,
                                              const int* __restrict__ srcs,
                                              const float* __restrict__ dinv,
                                              const float* __restrict__ b3,
                                              const int* __restrict__ choices,
                                              float* __restrict__ cbuf,
                                              float* __restrict__ pmax, int n) {
    __shared__ float red[BLK];
    int tid = threadIdx.x;
    int nl = tid >> 3, l8 = tid & 7;
    int i = blockIdx.x * 32 + nl;
    bool act = (i < n);
    float logit = -INFINITY;
    if (act) {
        float s = 0.f;
        int beg = offs[i], end = beg + degi[i];
        for (int j = beg + l8; j < end; j += 8) s += hws3[srcs[j]];
        s += __shfl_xor(s, 1);
        s += __shfl_xor(s, 2);
        s += __shfl_xor(s, 4);
        if (l8 == 0) {
            float c = dinv[i] * (s + 2.f * hws3[i]) + b3[0];
            cbuf[i] = c;
            if (choices[i] != 0) logit = c;
        }
    }
    red[tid] = logit;
    __syncthreads();
    for (int d = BLK / 2; d > 0; d >>= 1) {
        if (tid < d) red[tid] = fmaxf(red[tid], red[tid + d]);
        __syncthreads();
    }
    if (tid == 0) pmax[blockIdx.x] = red[0];
}

__global__ void k_redmax(const float* __restrict__ pmax, float* __restrict__ scal_m, int nblk) {
    __shared__ float red[BLK];
    float m = -INFINITY;
    for (int i = threadIdx.x; i < nblk; i += BLK) m = fmaxf(m, pmax[i]);
    red[threadIdx.x] = m;
    __syncthreads();
    for (int d = BLK / 2; d > 0; d >>= 1) {
        if (threadIdx.x < d) red[threadIdx.x] = fmaxf(red[threadIdx.x], red[threadIdx.x + d]);
        __syncthreads();
    }
    if (threadIdx.x == 0) scal_m[0] = red[0];
}

__global__ void __launch_bounds__(BLK) k_sumexp(const float* __restrict__ cbuf,
                                                const int* __restrict__ choices,
                                                const float* __restrict__ scal_m,
                                                float* __restrict__ Ssum, int n) {
    __shared__ float red[BLK];
    int i = blockIdx.x * BLK + threadIdx.x;
    float m = scal_m[0];
    float v = 0.0f;
    if (i < n && choices[i] != 0) v = expf(cbuf[i] - m);
    red[threadIdx.x] = v;
    __syncthreads();
    for (int d = BLK / 2; d > 0; d >>= 1) {
        if (threadIdx.x < d) red[threadIdx.x] += red[threadIdx.x + d];
        __syncthreads();
    }
    if (threadIdx.x == 0) atomicAdd(Ssum, red[0]);
}

__global__ void __launch_bounds__(BLK) k_final(const float* __restrict__ cbuf,
                                               const int* __restrict__ choices,
                                               const float* __restrict__ scal_m,
                                               const float* __restrict__ Ssum,
                                               const float* __restrict__ pool,
                                               const float* __restrict__ fcw,
                                               const float* __restrict__ fcb,
                                               float* __restrict__ out, int n) {
    int i = blockIdx.x * BLK + threadIdx.x;
    if (i < n) {
        float p = 0.0f;
        if (choices[i] != 0) {
            float m = scal_m[0], S = Ssum[0];
            p = expf(cbuf[i] - m) / S;
        }
        out[i] = p;
    }
    if (blockIdx.x == 0 && threadIdx.x == 0) {
        float invn = 1.0f / (float)n;
        float v = 0.0f;
#pragma unroll
        for (int f = 0; f < 16; f++) v += (pool[f] * invn) * fcw[f];
        out[n] = v + fcb[0];
    }
}

extern "C" void kernel_launch(void* const* d_in, const int* in_sizes, int n_in,
                              void* d_out, int out_size, void* d_ws, size_t ws_size,
                              hipStream_t stream) {
    const float* x       = (const float*)d_in[0];
    const int*   ei      = (const int*)d_in[1];
    const int*   choices = (const int*)d_in[2];
    const float* W1 = (const float*)d_in[3];
    const float* b1 = (const float*)d_in[4];
    const float* W2 = (const float*)d_in[5];
    const float* b2 = (const float*)d_in[6];
    const float* W3 = (const float*)d_in[7];
    const float* b3 = (const float*)d_in[8];
    const float* fcw = (const float*)d_in[9];
    const float* fcb = (const float*)d_in[10];
    float* out = (float*)d_out;

    int n = in_sizes[0] / 3;
    int E = in_sizes[1] / 2;
    const int* row = ei;
    const int* col = ei + E;

    int nblkN = (n + BLK - 1) / BLK;           // 391
    int nblk32 = (n + 31) / 32;                // 3125  (8 lanes/node kernels)
    int nbuck = (n + (1 << BSH) - 1) >> BSH;   // 196 buckets of 512 nodes
    int nblkBin = (E + EB - 1) / EB;           // 391 binning blocks

    // workspace layout (16B aligned slices)
    char* ws = (char*)d_ws;
    size_t o = 0;
    auto alloc = [&](size_t bytes) { char* p = ws + o; o += (bytes + 15) & ~(size_t)15; return p; };
    int*   degi   = (int*)  alloc((size_t)n * 4);
    int*   offs   = (int*)  alloc((size_t)n * 4);
    float* dinv   = (float*)alloc((size_t)n * 4);
    float* hws3   = (float*)alloc((size_t)n * 4);
    float* cbuf   = (float*)alloc((size_t)n * 4);
    float* pmax   = (float*)alloc(16384);      // >= nblk32 floats
    int*   bcnt   = (int*)  alloc(4096);
    int*   gcur   = (int*)  alloc(4096);
    int*   bbase  = (int*)  alloc(4096);
    float* scal   = (float*)alloc(256);   // [0]=S, [1..16]=pool, [17]=m
    float* Ssum   = scal + 0;
    float* pool   = scal + 1;
    float* scal_m = scal + 17;
    size_t hw_bytes = (size_t)n * 16 * 2 * 2;            // hwsA + hwsB (fp16)
    size_t pk_bytes = (size_t)E * 4;                     // packed (aliases hwsA/B)
    char*  blob   = alloc(hw_bytes > pk_bytes ? hw_bytes : pk_bytes);
    __half* hwsA  = (__half*)blob;
    __half* hwsB  = hwsA + (size_t)n * 16;
    int*   packed = (int*)blob;           // build phase only; dead before k_l1
    int*   srcs   = (int*)  alloc((size_t)E * 4);
    (void)ws_size;

    hipMemsetAsync(bcnt, 0, 1024, stream);
    hipMemsetAsync(scal, 0, 68, stream);   // S + pool[16]

    // ---- CSR build (no per-edge global atomics) ----
    k_bcount<<<nblkBin, BLK, 0, stream>>>(col, bcnt, E);
    k_bscan<<<1, 256, 0, stream>>>(bcnt, gcur, bbase, nbuck);
    k_bin<<<nblkBin, BINTH, 0, stream>>>(row, col, gcur, packed, E);
    k_place<<<nbuck, BLK, 0, stream>>>(packed, bbase, bcnt, degi, offs, dinv, srcs, n);

    // ---- GCN layers (8 lanes per node, fp16 payloads) ----
    k_l1<<<nblkN, BLK, 0, stream>>>(x, W1, dinv, hwsA, n);
    k_agg1<<<nblk32, BLK, 0, stream>>>(hwsA, offs, degi, srcs, dinv, b1, W2, hwsB, n);
    k_agg2<<<nblk32, BLK, 0, stream>>>(hwsB, offs, degi, srcs, dinv, b2, W3, hws3, pool, n);
    k_agg3<<<nblk32, BLK, 0, stream>>>(hws3, offs, degi, srcs, dinv, b3, choices, cbuf, pmax, n);

    // ---- softmax + value head ----
    k_redmax<<<1, BLK, 0, stream>>>(pmax, scal_m, nblk32);
    k_sumexp<<<nblkN, BLK, 0, stream>>>(cbuf, choices, scal_m, Ssum, n);
    k_final<<<nblkN, BLK, 0, stream>>>(cbuf, choices, scal_m, Ssum, pool, fcw, fcb, out, n);
}